// Round 13
// baseline (32.024 us; speedup 1.0000x reference)
//
#include <hip/hip_runtime.h>
#include <math.h>

#define WHVI_D 2048

typedef int   v2i __attribute__((ext_vector_type(2)));
typedef float v4f __attribute__((ext_vector_type(4)));

// ---------------------------------------------------------------------------
// Kernel 1: u[i] = (g_mu[i] + sqrt(softplus(g_rho[i])) * eps[i]) / 2048
// ---------------------------------------------------------------------------
__global__ __launch_bounds__(256) void whvi_u_kernel(
    const float* __restrict__ g_mu,
    const float* __restrict__ g_rho,
    const float* __restrict__ eps,
    float* __restrict__ u)
{
    int i = blockIdx.x * 256 + threadIdx.x;
    if (i >= WHVI_D) return;
    float r  = g_rho[i];
    float sp = fmaxf(r, 0.0f) + __logf(1.0f + __expf(-fabsf(r)));
    u[i] = fmaf(sqrtf(sp), eps[i], g_mu[i]) * (1.0f / 2048.0f);
}

// ---------------------------------------------------------------------------
// In-register butterfly over an N-reg dimension, xor-mask M.
// ---------------------------------------------------------------------------
template <int M, int N>
__device__ __forceinline__ void bfly_reg(float (&v)[N]) {
#pragma unroll
    for (int r = 0; r < N; ++r) {
        if (!(r & M)) {
            float a = v[r], c = v[r ^ M];
            v[r]     = a + c;
            v[r ^ M] = a - c;
        }
    }
}

// Lane-xor butterfly via DPP: p = v[lane^k]; v = sgn*v + p.
// CTRL: 0xB1 quad_perm [1,0,3,2] (xor1), 0x4E [2,3,0,1] (xor2), 0x128 row_ror:8 (xor8).
template <int CTRL, int N>
__device__ __forceinline__ void bfly_dpp(float (&v)[N], float sgn) {
#pragma unroll
    for (int r = 0; r < N; ++r) {
        int p = __builtin_amdgcn_mov_dpp(__float_as_int(v[r]), CTRL, 0xF, 0xF, false);
        v[r] = fmaf(sgn, v[r], __int_as_float(p));
    }
}

// Lane-xor-4 via ds_swizzle BitMode: offset = (4<<10)|31 = 0x101F.
template <int N>
__device__ __forceinline__ void bfly_swz4(float (&v)[N], float sgn) {
#pragma unroll
    for (int r = 0; r < N; ++r) {
        int p = __builtin_amdgcn_ds_swizzle(__float_as_int(v[r]), 0x101F);
        v[r] = fmaf(sgn, v[r], __int_as_float(p));
    }
}

// Lane-xor 16 / 32 via permlane16/32_swap pair trick.
template <bool IS32, int N>
__device__ __forceinline__ void bfly_permlane(float (&v)[N]) {
#pragma unroll
    for (int r = 0; r < N; r += 2) {
        int a = __float_as_int(v[r]), b = __float_as_int(v[r + 1]);
        v2i t;
        if constexpr (IS32) t = __builtin_amdgcn_permlane32_swap(a, b, false, false);
        else                t = __builtin_amdgcn_permlane16_swap(a, b, false, false);
        float s = __int_as_float(t.x) + __int_as_float(t.y);
        float d = __int_as_float(t.x) - __int_as_float(t.y);
        v2i wv;
        if constexpr (IS32) wv = __builtin_amdgcn_permlane32_swap(__float_as_int(s), __float_as_int(d), false, false);
        else                wv = __builtin_amdgcn_permlane16_swap(__float_as_int(s), __float_as_int(d), false, false);
        v[r]     = __int_as_float(wv.x);
        v[r + 1] = __int_as_float(wv.y);
    }
}

// FWHT-1024 on a half-row. Layout: reg r=j*4+c, lane L -> e = j*256 + L*4 + c.
// e bits: c=0..1 (reg M=1,2), L=2..7 (lane stages), j=8..9 (reg M=4,8).
__device__ __forceinline__ void fwht1024(float (&v)[16], float sg1, float sg2,
                                         float sg4, float sg8) {
    bfly_reg<1>(v); bfly_reg<2>(v); bfly_reg<4>(v); bfly_reg<8>(v);
    bfly_dpp<0xB1>(v, sg1);     // e bit 2
    bfly_dpp<0x4E>(v, sg2);     // e bit 3
    bfly_swz4(v, sg4);          // e bit 4
    bfly_dpp<0x128>(v, sg8);    // e bit 5
    bfly_permlane<false>(v);    // e bit 6
    bfly_permlane<true>(v);     // e bit 7
}

__device__ __forceinline__ float4 ld4(const float* p) {
    return *reinterpret_cast<const float4*>(p);
}

// ---------------------------------------------------------------------------
// Half-row per wave: 16384 waves = 2x the chip's 8192 wave slots, so the
// scheduler pipelines two full generations — gen-2 x-loads overlap gen-1's
// store drain (the phase-lock that capped R8/R10 at ~28 us). H2048 = H2 (x)
// H1024: local FWHT-1024 per wave; the single cross-wave stage FUSES with the
// u-multiply into one LDS exchange + the uniform formula
//   out = (a+b)*u_lo + (a-b)*u_hi      (a = own half, b = partner half)
// which is identical for both waves (no divergence). One __syncthreads.
// 16 KB LDS/block -> 8 blocks/CU = 32 waves/CU co-resident, 4096 blocks total.
// Broadcasts (s2, u, s1) from L1/L2-hot global; u precomputed by kernel 1.
// ---------------------------------------------------------------------------
__global__ __launch_bounds__(256) void whvi_main_kernel(
    const float* __restrict__ x,
    const float* __restrict__ s1,
    const float* __restrict__ s2,
    const float* __restrict__ u,
    float* __restrict__ out)
{
    __shared__ __align__(16) float xch[4][1024];   // 16 KB exchange

    const int  tid  = threadIdx.x;
    const int  wid  = tid >> 6;
    const int  lane = tid & 63;
    const int  lo   = lane * 4;
    const int  h    = wid & 1;        // which half of the row
    const long row  = (long)blockIdx.x * 2 + (wid >> 1);
    const int  hb   = h << 10;        // half base offset (0 or 1024)

    const float* xr = x + row * WHVI_D + hb;

    // ---- 4 coalesced x loads for this half-row ----
    float4 xa = ld4(xr + 0 * 256 + lo);
    float4 xb = ld4(xr + 1 * 256 + lo);
    float4 xc = ld4(xr + 2 * 256 + lo);
    float4 xd = ld4(xr + 3 * 256 + lo);

    const float sg1 = (lane & 1) ? -1.0f : 1.0f;
    const float sg2 = (lane & 2) ? -1.0f : 1.0f;
    const float sg4 = (lane & 4) ? -1.0f : 1.0f;
    const float sg8 = (lane & 8) ? -1.0f : 1.0f;

    // ---- v = x * s2 (s2 slice L1-hot) ----
    float v[16];
    {
        const float* s2h = s2 + hb;
        float4 sv;
        sv = ld4(s2h + 0 * 256 + lo);
        v[ 0] = xa.x * sv.x; v[ 1] = xa.y * sv.y; v[ 2] = xa.z * sv.z; v[ 3] = xa.w * sv.w;
        sv = ld4(s2h + 1 * 256 + lo);
        v[ 4] = xb.x * sv.x; v[ 5] = xb.y * sv.y; v[ 6] = xb.z * sv.z; v[ 7] = xb.w * sv.w;
        sv = ld4(s2h + 2 * 256 + lo);
        v[ 8] = xc.x * sv.x; v[ 9] = xc.y * sv.y; v[10] = xc.z * sv.z; v[11] = xc.w * sv.w;
        sv = ld4(s2h + 3 * 256 + lo);
        v[12] = xd.x * sv.x; v[13] = xd.y * sv.y; v[14] = xd.z * sv.z; v[15] = xd.w * sv.w;
    }

    // ---- FWHT #1, local 1024 part ----
    fwht1024(v, sg1, sg2, sg4, sg8);

    // ---- exchange halves ----
#pragma unroll
    for (int j = 0; j < 4; ++j) {
        v4f t = { v[j * 4 + 0], v[j * 4 + 1], v[j * 4 + 2], v[j * 4 + 3] };
        *reinterpret_cast<v4f*>(&xch[wid][j * 256 + lo]) = t;
    }
    __syncthreads();

    // ---- fused cross-stage(bit10) + u-mult + cross-stage(bit10):
    //      out = (a+b)*u_lo + (a-b)*u_hi  — uniform for both halves ----
    const int pid = wid ^ 1;
#pragma unroll
    for (int j = 0; j < 4; ++j) {
        const float4 b   = ld4(&xch[pid][j * 256 + lo]);
        const float4 ulo = ld4(u + j * 256 + lo);
        const float4 uhi = ld4(u + 1024 + j * 256 + lo);
        float a, s, d;
        a = v[j * 4 + 0]; s = a + b.x; d = a - b.x; v[j * 4 + 0] = fmaf(s, ulo.x, d * uhi.x);
        a = v[j * 4 + 1]; s = a + b.y; d = a - b.y; v[j * 4 + 1] = fmaf(s, ulo.y, d * uhi.y);
        a = v[j * 4 + 2]; s = a + b.z; d = a - b.z; v[j * 4 + 2] = fmaf(s, ulo.z, d * uhi.z);
        a = v[j * 4 + 3]; s = a + b.w; d = a - b.w; v[j * 4 + 3] = fmaf(s, ulo.w, d * uhi.w);
    }

    // ---- FWHT #2, local 1024 part ----
    fwht1024(v, sg1, sg2, sg4, sg8);

    // ---- epilogue: s1 (L1-hot), nontemporal store ----
    const float* s1h = s1 + hb;
    float* orow = out + row * WHVI_D + hb;
#pragma unroll
    for (int j = 0; j < 4; ++j) {
        const float4 sv = ld4(s1h + j * 256 + lo);
        v4f ov;
        ov.x = v[j * 4 + 0] * sv.x;
        ov.y = v[j * 4 + 1] * sv.y;
        ov.z = v[j * 4 + 2] * sv.z;
        ov.w = v[j * 4 + 3] * sv.w;
        __builtin_nontemporal_store(ov, reinterpret_cast<v4f*>(orow + j * 256 + lo));
    }
}

extern "C" void kernel_launch(void* const* d_in, const int* in_sizes, int n_in,
                              void* d_out, int out_size, void* d_ws, size_t ws_size,
                              hipStream_t stream)
{
    const float* x     = (const float*)d_in[0];
    const float* s1    = (const float*)d_in[1];
    const float* s2    = (const float*)d_in[2];
    const float* g_mu  = (const float*)d_in[3];
    const float* g_rho = (const float*)d_in[4];
    const float* eps   = (const float*)d_in[5];
    // d_in[6] = H unused: fast Walsh-Hadamard transform instead.

    float* u    = (float*)d_ws;     // 2048 floats scratch
    float* outp = (float*)d_out;

    whvi_u_kernel<<<8, 256, 0, stream>>>(g_mu, g_rho, eps, u);

    const int rows = out_size / WHVI_D;              // 8192
    whvi_main_kernel<<<rows / 2, 256, 0, stream>>>(x, s1, s2, u, outp);
}

// Round 14
// 31.660 us; speedup vs baseline: 1.0115x; 1.0115x over previous
//
#include <hip/hip_runtime.h>
#include <math.h>

#define WHVI_D 2048

typedef int   v2i __attribute__((ext_vector_type(2)));
typedef float v4f __attribute__((ext_vector_type(4)));

// ---------------------------------------------------------------------------
// In-register butterfly over the 32-reg dimension, xor-mask M (i bits 0,1,8,9,10).
// ---------------------------------------------------------------------------
template <int M>
__device__ __forceinline__ void bfly_reg(float (&v)[32]) {
#pragma unroll
    for (int r = 0; r < 32; ++r) {
        if (!(r & M)) {
            float a = v[r], c = v[r ^ M];
            v[r]     = a + c;
            v[r ^ M] = a - c;
        }
    }
}

// ---------------------------------------------------------------------------
// Lane-xor butterfly via DPP (VALU pipe): p = v[lane^k]; v = sgn*v + p.
// CTRL: 0xB1 = quad_perm [1,0,3,2] (xor1), 0x4E = [2,3,0,1] (xor2),
//       0x128 = row_ror:8 (xor8 within 16-lane rows).
// ---------------------------------------------------------------------------
template <int CTRL>
__device__ __forceinline__ void bfly_dpp(float (&v)[32], float sgn) {
#pragma unroll
    for (int r = 0; r < 32; ++r) {
        int p = __builtin_amdgcn_mov_dpp(__float_as_int(v[r]), CTRL, 0xF, 0xF, false);
        v[r] = fmaf(sgn, v[r], __int_as_float(p));
    }
}

// Lane-xor-4 via ds_swizzle BitMode: offset = (4<<10)|(0<<5)|31 = 0x101F.
__device__ __forceinline__ void bfly_swz4(float (&v)[32], float sgn) {
#pragma unroll
    for (int r = 0; r < 32; ++r) {
        int p = __builtin_amdgcn_ds_swizzle(__float_as_int(v[r]), 0x101F);
        v[r] = fmaf(sgn, v[r], __int_as_float(p));
    }
}

// ---------------------------------------------------------------------------
// Lane-xor 16 / 32 via v_permlane16/32_swap_b32 pair trick (2 regs at a time):
// swap(a,b); s=a'+b', d=a'-b'; swap(s,d) -> butterfly results for both regs.
// ---------------------------------------------------------------------------
template <bool IS32>
__device__ __forceinline__ void bfly_permlane(float (&v)[32]) {
#pragma unroll
    for (int r = 0; r < 32; r += 2) {
        int a = __float_as_int(v[r]), b = __float_as_int(v[r + 1]);
        v2i t;
        if constexpr (IS32) t = __builtin_amdgcn_permlane32_swap(a, b, false, false);
        else                t = __builtin_amdgcn_permlane16_swap(a, b, false, false);
        float s = __int_as_float(t.x) + __int_as_float(t.y);
        float d = __int_as_float(t.x) - __int_as_float(t.y);
        v2i wv;
        if constexpr (IS32) wv = __builtin_amdgcn_permlane32_swap(__float_as_int(s), __float_as_int(d), false, false);
        else                wv = __builtin_amdgcn_permlane16_swap(__float_as_int(s), __float_as_int(d), false, false);
        v[r]     = __int_as_float(wv.x);
        v[r + 1] = __int_as_float(wv.y);
    }
}

// Full 2048-point FWHT, layout P: reg r=j*4+c, lane L -> i = j*256 + L*4 + c.
__device__ __forceinline__ void fwht(float (&v)[32], float sg1, float sg2,
                                     float sg4, float sg8) {
    bfly_reg<1>(v); bfly_reg<2>(v); bfly_reg<4>(v); bfly_reg<8>(v); bfly_reg<16>(v);
    bfly_dpp<0xB1>(v, sg1);    // i bit 2
    bfly_dpp<0x4E>(v, sg2);    // i bit 3
    bfly_swz4(v, sg4);         // i bit 4
    bfly_dpp<0x128>(v, sg8);   // i bit 5
    bfly_permlane<false>(v);   // i bit 6
    bfly_permlane<true>(v);    // i bit 7
}

__device__ __forceinline__ float4 ld4(const float* p) {
    return *reinterpret_cast<const float4*>(p);
}

// ---------------------------------------------------------------------------
// R10 structure (champion, 28.05 us) + explicit time-domain cohort stagger:
// odd blocks sleep ~4.8 us before doing anything, so on each CU the odd
// cohort's load ramp overlaps the even cohort's compute/store phase and the
// two cohorts pipeline instead of phase-locking (8192 waves are exactly
// co-resident -> without this, loads/compute/stores globally serialize).
// 1 row/wave, u+s2 in 16 KB LDS, s1 global epilogue, nontemporal stores.
// ---------------------------------------------------------------------------
__global__ __launch_bounds__(256) void whvi_main_kernel(
    const float* __restrict__ x,
    const float* __restrict__ s1,
    const float* __restrict__ s2,
    const float* __restrict__ g_mu,
    const float* __restrict__ g_rho,
    const float* __restrict__ eps,
    float* __restrict__ out)
{
    __shared__ __align__(16) float sU[WHVI_D];
    __shared__ __align__(16) float sS2[WHVI_D];

    // ---- cohort stagger: odd blocks sleep ~11.5k cycles (~4.8 us) ----
    if (blockIdx.x & 1) {
        __builtin_amdgcn_s_sleep(90);
        __builtin_amdgcn_s_sleep(90);
    }

    const int  tid  = threadIdx.x;
    const int  wid  = tid >> 6;
    const int  lane = tid & 63;
    const int  lo   = lane * 4;
    const long row  = (long)blockIdx.x * 4 + wid;

    const float* xr = x + row * WHVI_D;

    // ---- batch 0: first 4 x-loads (longest latency path) ----
    float4 xa = ld4(xr + 0 * 256 + lo);
    float4 xb = ld4(xr + 1 * 256 + lo);
    float4 xc = ld4(xr + 2 * 256 + lo);
    float4 xd = ld4(xr + 3 * 256 + lo);

    // ---- cooperative staging of s2, u into LDS (hides under x latency) ----
#pragma unroll
    for (int k = 0; k < 2; ++k) {
        const int o = (k * 256 + tid) * 4;
        *reinterpret_cast<float4*>(&sS2[o]) = ld4(s2 + o);
        const float4 rv = ld4(g_rho + o);
        const float4 ev = ld4(eps + o);
        const float4 mv = ld4(g_mu + o);
        float4 u;
        float sp;
        sp  = fmaxf(rv.x, 0.0f) + __logf(1.0f + __expf(-fabsf(rv.x)));
        u.x = fmaf(sqrtf(sp), ev.x, mv.x) * (1.0f / 2048.0f);
        sp  = fmaxf(rv.y, 0.0f) + __logf(1.0f + __expf(-fabsf(rv.y)));
        u.y = fmaf(sqrtf(sp), ev.y, mv.y) * (1.0f / 2048.0f);
        sp  = fmaxf(rv.z, 0.0f) + __logf(1.0f + __expf(-fabsf(rv.z)));
        u.z = fmaf(sqrtf(sp), ev.z, mv.z) * (1.0f / 2048.0f);
        sp  = fmaxf(rv.w, 0.0f) + __logf(1.0f + __expf(-fabsf(rv.w)));
        u.w = fmaf(sqrtf(sp), ev.w, mv.w) * (1.0f / 2048.0f);
        *reinterpret_cast<float4*>(&sU[o]) = u;
    }
    __syncthreads();

    const float sg1 = (lane & 1) ? -1.0f : 1.0f;
    const float sg2 = (lane & 2) ? -1.0f : 1.0f;
    const float sg4 = (lane & 4) ? -1.0f : 1.0f;
    const float sg8 = (lane & 8) ? -1.0f : 1.0f;

    float v[32];

    // ---- batch 1 issued, then batch 0 consumed (frees its regs) ----
    float4 xe = ld4(xr + 4 * 256 + lo);
    float4 xf = ld4(xr + 5 * 256 + lo);
    float4 xg = ld4(xr + 6 * 256 + lo);
    float4 xh = ld4(xr + 7 * 256 + lo);

    {
        float4 sv;
        sv = ld4(&sS2[0 * 256 + lo]);
        v[ 0] = xa.x * sv.x; v[ 1] = xa.y * sv.y; v[ 2] = xa.z * sv.z; v[ 3] = xa.w * sv.w;
        sv = ld4(&sS2[1 * 256 + lo]);
        v[ 4] = xb.x * sv.x; v[ 5] = xb.y * sv.y; v[ 6] = xb.z * sv.z; v[ 7] = xb.w * sv.w;
        sv = ld4(&sS2[2 * 256 + lo]);
        v[ 8] = xc.x * sv.x; v[ 9] = xc.y * sv.y; v[10] = xc.z * sv.z; v[11] = xc.w * sv.w;
        sv = ld4(&sS2[3 * 256 + lo]);
        v[12] = xd.x * sv.x; v[13] = xd.y * sv.y; v[14] = xd.z * sv.z; v[15] = xd.w * sv.w;
        sv = ld4(&sS2[4 * 256 + lo]);
        v[16] = xe.x * sv.x; v[17] = xe.y * sv.y; v[18] = xe.z * sv.z; v[19] = xe.w * sv.w;
        sv = ld4(&sS2[5 * 256 + lo]);
        v[20] = xf.x * sv.x; v[21] = xf.y * sv.y; v[22] = xf.z * sv.z; v[23] = xf.w * sv.w;
        sv = ld4(&sS2[6 * 256 + lo]);
        v[24] = xg.x * sv.x; v[25] = xg.y * sv.y; v[26] = xg.z * sv.z; v[27] = xg.w * sv.w;
        sv = ld4(&sS2[7 * 256 + lo]);
        v[28] = xh.x * sv.x; v[29] = xh.y * sv.y; v[30] = xh.z * sv.z; v[31] = xh.w * sv.w;
    }

    fwht(v, sg1, sg2, sg4, sg8);

#pragma unroll
    for (int j = 0; j < 8; ++j) {
        const float4 uv = ld4(&sU[j * 256 + lo]);
        v[j * 4 + 0] *= uv.x;
        v[j * 4 + 1] *= uv.y;
        v[j * 4 + 2] *= uv.z;
        v[j * 4 + 3] *= uv.w;
    }

    fwht(v, sg1, sg2, sg4, sg8);

    // ---- epilogue: s1 from global (L1-hot), nontemporal store ----
    float* orow = out + row * WHVI_D;
#pragma unroll
    for (int j = 0; j < 8; ++j) {
        const float4 sv = ld4(s1 + j * 256 + lo);
        v4f ov;
        ov.x = v[j * 4 + 0] * sv.x;
        ov.y = v[j * 4 + 1] * sv.y;
        ov.z = v[j * 4 + 2] * sv.z;
        ov.w = v[j * 4 + 3] * sv.w;
        __builtin_nontemporal_store(ov, reinterpret_cast<v4f*>(orow + j * 256 + lo));
    }
}

extern "C" void kernel_launch(void* const* d_in, const int* in_sizes, int n_in,
                              void* d_out, int out_size, void* d_ws, size_t ws_size,
                              hipStream_t stream)
{
    const float* x     = (const float*)d_in[0];
    const float* s1    = (const float*)d_in[1];
    const float* s2    = (const float*)d_in[2];
    const float* g_mu  = (const float*)d_in[3];
    const float* g_rho = (const float*)d_in[4];
    const float* eps   = (const float*)d_in[5];
    // d_in[6] = H unused: fast Walsh-Hadamard transform instead.

    float* outp = (float*)d_out;
    const int rows = out_size / WHVI_D;              // 8192
    whvi_main_kernel<<<rows / 4, 256, 0, stream>>>(x, s1, s2, g_mu, g_rho, eps, outp);
}

// Round 15
// 29.170 us; speedup vs baseline: 1.0978x; 1.0854x over previous
//
#include <hip/hip_runtime.h>
#include <math.h>

#define WHVI_D 2048

typedef int   v2i __attribute__((ext_vector_type(2)));
typedef float f2  __attribute__((ext_vector_type(2)));
typedef float v4f __attribute__((ext_vector_type(4)));

// ---------------------------------------------------------------------------
// Packed butterfly on two adjacent register pairs (M >= 2): <2 x float> ops
// select double-rate v_pk_add_f32 on gfx950 — halves reg-stage instructions.
// ---------------------------------------------------------------------------
__device__ __forceinline__ void pk_bfly(float &a0, float &a1, float &b0, float &b1) {
    f2 a = {a0, a1}, b = {b0, b1};
    f2 s = a + b;
    f2 d = a - b;
    a0 = s.x; a1 = s.y; b0 = d.x; b1 = d.y;
}

// In-register butterfly over the 32-reg dimension, xor-mask M (i bits 0,1,8,9,10).
// M==1 mixes within a pair (scalar); M>=2 is pair-aligned (packed).
template <int M>
__device__ __forceinline__ void bfly_reg(float (&v)[32]) {
    if constexpr (M == 1) {
#pragma unroll
        for (int r = 0; r < 32; r += 2) {
            float a = v[r], c = v[r + 1];
            v[r]     = a + c;
            v[r + 1] = a - c;
        }
    } else {
#pragma unroll
        for (int r = 0; r < 32; r += 2) {
            if (!(r & M))
                pk_bfly(v[r], v[r + 1], v[r ^ M], v[(r ^ M) + 1]);
        }
    }
}

// ---------------------------------------------------------------------------
// Lane-xor butterfly via DPP (VALU pipe): p = v[lane^k]; v = sgn*v + p.
// CTRL: 0xB1 = quad_perm [1,0,3,2] (xor1), 0x4E = [2,3,0,1] (xor2),
//       0x128 = row_ror:8 (xor8 within 16-lane rows).
// ---------------------------------------------------------------------------
template <int CTRL>
__device__ __forceinline__ void bfly_dpp(float (&v)[32], float sgn) {
#pragma unroll
    for (int r = 0; r < 32; ++r) {
        int p = __builtin_amdgcn_mov_dpp(__float_as_int(v[r]), CTRL, 0xF, 0xF, false);
        v[r] = fmaf(sgn, v[r], __int_as_float(p));
    }
}

// Lane-xor-4 via ds_swizzle BitMode: offset = (4<<10)|(0<<5)|31 = 0x101F.
__device__ __forceinline__ void bfly_swz4(float (&v)[32], float sgn) {
#pragma unroll
    for (int r = 0; r < 32; ++r) {
        int p = __builtin_amdgcn_ds_swizzle(__float_as_int(v[r]), 0x101F);
        v[r] = fmaf(sgn, v[r], __int_as_float(p));
    }
}

// ---------------------------------------------------------------------------
// Lane-xor 16 / 32 via v_permlane16/32_swap_b32 pair trick (2 regs at a time):
// swap(a,b); s=a'+b', d=a'-b'; swap(s,d) -> butterfly results for both regs.
// ---------------------------------------------------------------------------
template <bool IS32>
__device__ __forceinline__ void bfly_permlane(float (&v)[32]) {
#pragma unroll
    for (int r = 0; r < 32; r += 2) {
        int a = __float_as_int(v[r]), b = __float_as_int(v[r + 1]);
        v2i t;
        if constexpr (IS32) t = __builtin_amdgcn_permlane32_swap(a, b, false, false);
        else                t = __builtin_amdgcn_permlane16_swap(a, b, false, false);
        float s = __int_as_float(t.x) + __int_as_float(t.y);
        float d = __int_as_float(t.x) - __int_as_float(t.y);
        v2i wv;
        if constexpr (IS32) wv = __builtin_amdgcn_permlane32_swap(__float_as_int(s), __float_as_int(d), false, false);
        else                wv = __builtin_amdgcn_permlane16_swap(__float_as_int(s), __float_as_int(d), false, false);
        v[r]     = __int_as_float(wv.x);
        v[r + 1] = __int_as_float(wv.y);
    }
}

// Full 2048-point FWHT, layout P: reg r=j*4+c, lane L -> i = j*256 + L*4 + c.
__device__ __forceinline__ void fwht(float (&v)[32], float sg1, float sg2,
                                     float sg4, float sg8) {
    bfly_reg<1>(v); bfly_reg<2>(v); bfly_reg<4>(v); bfly_reg<8>(v); bfly_reg<16>(v);
    bfly_dpp<0xB1>(v, sg1);    // i bit 2
    bfly_dpp<0x4E>(v, sg2);    // i bit 3
    bfly_swz4(v, sg4);         // i bit 4
    bfly_dpp<0x128>(v, sg8);   // i bit 5
    bfly_permlane<false>(v);   // i bit 6
    bfly_permlane<true>(v);    // i bit 7
}

__device__ __forceinline__ float4 ld4(const float* p) {
    return *reinterpret_cast<const float4*>(p);
}

// packed elementwise: {v0,v1} *= {a,b}  (v_pk_mul_f32)
__device__ __forceinline__ void pk_mul(float &v0, float &v1, float a, float b) {
    f2 p = f2{v0, v1} * f2{a, b};
    v0 = p.x; v1 = p.y;
}

// ---------------------------------------------------------------------------
// R10 champion structure, packed-math only change. 1 row per wave, 2048
// blocks, u+s2 staged in 16 KB LDS once per block; s1 read from global in the
// epilogue (L1-hot); x loaded in two immediate-consume batches; nontemporal
// stores (load-bearing: keeps out-writebacks from evicting the x stream).
// ---------------------------------------------------------------------------
__global__ __launch_bounds__(256) void whvi_main_kernel(
    const float* __restrict__ x,
    const float* __restrict__ s1,
    const float* __restrict__ s2,
    const float* __restrict__ g_mu,
    const float* __restrict__ g_rho,
    const float* __restrict__ eps,
    float* __restrict__ out)
{
    __shared__ __align__(16) float sU[WHVI_D];
    __shared__ __align__(16) float sS2[WHVI_D];

    const int  tid  = threadIdx.x;
    const int  wid  = tid >> 6;
    const int  lane = tid & 63;
    const int  lo   = lane * 4;
    const long row  = (long)blockIdx.x * 4 + wid;

    const float* xr = x + row * WHVI_D;

    // ---- batch 0: first 4 x-loads (longest latency path) ----
    float4 xa = ld4(xr + 0 * 256 + lo);
    float4 xb = ld4(xr + 1 * 256 + lo);
    float4 xc = ld4(xr + 2 * 256 + lo);
    float4 xd = ld4(xr + 3 * 256 + lo);

    // ---- cooperative staging of s2, u into LDS (hides under x latency) ----
#pragma unroll
    for (int k = 0; k < 2; ++k) {
        const int o = (k * 256 + tid) * 4;
        *reinterpret_cast<float4*>(&sS2[o]) = ld4(s2 + o);
        const float4 rv = ld4(g_rho + o);
        const float4 ev = ld4(eps + o);
        const float4 mv = ld4(g_mu + o);
        float4 u;
        float sp;
        sp  = fmaxf(rv.x, 0.0f) + __logf(1.0f + __expf(-fabsf(rv.x)));
        u.x = fmaf(sqrtf(sp), ev.x, mv.x) * (1.0f / 2048.0f);
        sp  = fmaxf(rv.y, 0.0f) + __logf(1.0f + __expf(-fabsf(rv.y)));
        u.y = fmaf(sqrtf(sp), ev.y, mv.y) * (1.0f / 2048.0f);
        sp  = fmaxf(rv.z, 0.0f) + __logf(1.0f + __expf(-fabsf(rv.z)));
        u.z = fmaf(sqrtf(sp), ev.z, mv.z) * (1.0f / 2048.0f);
        sp  = fmaxf(rv.w, 0.0f) + __logf(1.0f + __expf(-fabsf(rv.w)));
        u.w = fmaf(sqrtf(sp), ev.w, mv.w) * (1.0f / 2048.0f);
        *reinterpret_cast<float4*>(&sU[o]) = u;
    }
    __syncthreads();

    const float sg1 = (lane & 1) ? -1.0f : 1.0f;
    const float sg2 = (lane & 2) ? -1.0f : 1.0f;
    const float sg4 = (lane & 4) ? -1.0f : 1.0f;
    const float sg8 = (lane & 8) ? -1.0f : 1.0f;

    float v[32];

    // ---- batch 1 issued, then batch 0 consumed (frees its regs) ----
    float4 xe = ld4(xr + 4 * 256 + lo);
    float4 xf = ld4(xr + 5 * 256 + lo);
    float4 xg = ld4(xr + 6 * 256 + lo);
    float4 xh = ld4(xr + 7 * 256 + lo);

    {
        float4 sv;
        sv = ld4(&sS2[0 * 256 + lo]);
        v[ 0] = xa.x * sv.x; v[ 1] = xa.y * sv.y; v[ 2] = xa.z * sv.z; v[ 3] = xa.w * sv.w;
        sv = ld4(&sS2[1 * 256 + lo]);
        v[ 4] = xb.x * sv.x; v[ 5] = xb.y * sv.y; v[ 6] = xb.z * sv.z; v[ 7] = xb.w * sv.w;
        sv = ld4(&sS2[2 * 256 + lo]);
        v[ 8] = xc.x * sv.x; v[ 9] = xc.y * sv.y; v[10] = xc.z * sv.z; v[11] = xc.w * sv.w;
        sv = ld4(&sS2[3 * 256 + lo]);
        v[12] = xd.x * sv.x; v[13] = xd.y * sv.y; v[14] = xd.z * sv.z; v[15] = xd.w * sv.w;
        sv = ld4(&sS2[4 * 256 + lo]);
        v[16] = xe.x * sv.x; v[17] = xe.y * sv.y; v[18] = xe.z * sv.z; v[19] = xe.w * sv.w;
        sv = ld4(&sS2[5 * 256 + lo]);
        v[20] = xf.x * sv.x; v[21] = xf.y * sv.y; v[22] = xf.z * sv.z; v[23] = xf.w * sv.w;
        sv = ld4(&sS2[6 * 256 + lo]);
        v[24] = xg.x * sv.x; v[25] = xg.y * sv.y; v[26] = xg.z * sv.z; v[27] = xg.w * sv.w;
        sv = ld4(&sS2[7 * 256 + lo]);
        v[28] = xh.x * sv.x; v[29] = xh.y * sv.y; v[30] = xh.z * sv.z; v[31] = xh.w * sv.w;
    }

    fwht(v, sg1, sg2, sg4, sg8);

#pragma unroll
    for (int j = 0; j < 8; ++j) {
        const float4 uv = ld4(&sU[j * 256 + lo]);
        pk_mul(v[j * 4 + 0], v[j * 4 + 1], uv.x, uv.y);
        pk_mul(v[j * 4 + 2], v[j * 4 + 3], uv.z, uv.w);
    }

    fwht(v, sg1, sg2, sg4, sg8);

    // ---- epilogue: s1 from global (L1-hot), nontemporal store ----
    float* orow = out + row * WHVI_D;
#pragma unroll
    for (int j = 0; j < 8; ++j) {
        const float4 sv = ld4(s1 + j * 256 + lo);
        v4f ov;
        ov.x = v[j * 4 + 0] * sv.x;
        ov.y = v[j * 4 + 1] * sv.y;
        ov.z = v[j * 4 + 2] * sv.z;
        ov.w = v[j * 4 + 3] * sv.w;
        __builtin_nontemporal_store(ov, reinterpret_cast<v4f*>(orow + j * 256 + lo));
    }
}

extern "C" void kernel_launch(void* const* d_in, const int* in_sizes, int n_in,
                              void* d_out, int out_size, void* d_ws, size_t ws_size,
                              hipStream_t stream)
{
    const float* x     = (const float*)d_in[0];
    const float* s1    = (const float*)d_in[1];
    const float* s2    = (const float*)d_in[2];
    const float* g_mu  = (const float*)d_in[3];
    const float* g_rho = (const float*)d_in[4];
    const float* eps   = (const float*)d_in[5];
    // d_in[6] = H unused: fast Walsh-Hadamard transform instead.

    float* outp = (float*)d_out;
    const int rows = out_size / WHVI_D;              // 8192
    whvi_main_kernel<<<rows / 4, 256, 0, stream>>>(x, s1, s2, g_mu, g_rho, eps, outp);
}

// Round 16
// 27.825 us; speedup vs baseline: 1.1509x; 1.0483x over previous
//
#include <hip/hip_runtime.h>
#include <math.h>

#define WHVI_D 2048

typedef int   v2i __attribute__((ext_vector_type(2)));
typedef float v4f __attribute__((ext_vector_type(4)));

// ---------------------------------------------------------------------------
// In-register butterfly over the 32-reg dimension, xor-mask M (i bits 0,1,8,9,10).
// ---------------------------------------------------------------------------
template <int M>
__device__ __forceinline__ void bfly_reg(float (&v)[32]) {
#pragma unroll
    for (int r = 0; r < 32; ++r) {
        if (!(r & M)) {
            float a = v[r], c = v[r ^ M];
            v[r]     = a + c;
            v[r ^ M] = a - c;
        }
    }
}

// ---------------------------------------------------------------------------
// Lane-xor butterfly via DPP (VALU pipe): p = v[lane^k]; v = sgn*v + p.
// CTRL: 0xB1 = quad_perm [1,0,3,2] (xor1), 0x4E = [2,3,0,1] (xor2),
//       0x128 = row_ror:8 (xor8 within 16-lane rows).
// ---------------------------------------------------------------------------
template <int CTRL>
__device__ __forceinline__ void bfly_dpp(float (&v)[32], float sgn) {
#pragma unroll
    for (int r = 0; r < 32; ++r) {
        int p = __builtin_amdgcn_mov_dpp(__float_as_int(v[r]), CTRL, 0xF, 0xF, false);
        v[r] = fmaf(sgn, v[r], __int_as_float(p));
    }
}

// Lane-xor-4 via ds_swizzle BitMode: offset = (4<<10)|(0<<5)|31 = 0x101F.
__device__ __forceinline__ void bfly_swz4(float (&v)[32], float sgn) {
#pragma unroll
    for (int r = 0; r < 32; ++r) {
        int p = __builtin_amdgcn_ds_swizzle(__float_as_int(v[r]), 0x101F);
        v[r] = fmaf(sgn, v[r], __int_as_float(p));
    }
}

// ---------------------------------------------------------------------------
// Lane-xor 16 / 32 via v_permlane16/32_swap_b32 pair trick (2 regs at a time):
// swap(a,b); s=a'+b', d=a'-b'; swap(s,d) -> butterfly results for both regs.
// ---------------------------------------------------------------------------
template <bool IS32>
__device__ __forceinline__ void bfly_permlane(float (&v)[32]) {
#pragma unroll
    for (int r = 0; r < 32; r += 2) {
        int a = __float_as_int(v[r]), b = __float_as_int(v[r + 1]);
        v2i t;
        if constexpr (IS32) t = __builtin_amdgcn_permlane32_swap(a, b, false, false);
        else                t = __builtin_amdgcn_permlane16_swap(a, b, false, false);
        float s = __int_as_float(t.x) + __int_as_float(t.y);
        float d = __int_as_float(t.x) - __int_as_float(t.y);
        v2i wv;
        if constexpr (IS32) wv = __builtin_amdgcn_permlane32_swap(__float_as_int(s), __float_as_int(d), false, false);
        else                wv = __builtin_amdgcn_permlane16_swap(__float_as_int(s), __float_as_int(d), false, false);
        v[r]     = __int_as_float(wv.x);
        v[r + 1] = __int_as_float(wv.y);
    }
}

// Full 2048-point FWHT, layout P: reg r=j*4+c, lane L -> i = j*256 + L*4 + c.
__device__ __forceinline__ void fwht(float (&v)[32], float sg1, float sg2,
                                     float sg4, float sg8) {
    bfly_reg<1>(v); bfly_reg<2>(v); bfly_reg<4>(v); bfly_reg<8>(v); bfly_reg<16>(v);
    bfly_dpp<0xB1>(v, sg1);    // i bit 2
    bfly_dpp<0x4E>(v, sg2);    // i bit 3
    bfly_swz4(v, sg4);         // i bit 4
    bfly_dpp<0x128>(v, sg8);   // i bit 5
    bfly_permlane<false>(v);   // i bit 6
    bfly_permlane<true>(v);    // i bit 7
}

__device__ __forceinline__ float4 ld4(const float* p) {
    return *reinterpret_cast<const float4*>(p);
}

// ---------------------------------------------------------------------------
// Champion configuration (R10, 28.05 us). 1 row per wave, 2048 blocks (8/CU,
// 32 waves/CU — the whole problem exactly co-resident; measured max-TLP
// optimum over 8 structural variants). u and s2 staged in 16 KB LDS once per
// block (broadcasts ride the DS pipe); s1 read from global in the epilogue
// (L1-hot, ~0 cost vs LDS per R8 A/B); x loaded in two immediate-consume
// batches (VGPR ~64, no launch-bounds arg2 -> no 64-VGPR clamp/spill);
// nontemporal stores (load-bearing: out writebacks would evict the x stream,
// +2.4 us measured in R12).
// ---------------------------------------------------------------------------
__global__ __launch_bounds__(256) void whvi_main_kernel(
    const float* __restrict__ x,
    const float* __restrict__ s1,
    const float* __restrict__ s2,
    const float* __restrict__ g_mu,
    const float* __restrict__ g_rho,
    const float* __restrict__ eps,
    float* __restrict__ out)
{
    __shared__ __align__(16) float sU[WHVI_D];
    __shared__ __align__(16) float sS2[WHVI_D];

    const int  tid  = threadIdx.x;
    const int  wid  = tid >> 6;
    const int  lane = tid & 63;
    const int  lo   = lane * 4;
    const long row  = (long)blockIdx.x * 4 + wid;

    const float* xr = x + row * WHVI_D;

    // ---- batch 0: first 4 x-loads (longest latency path) ----
    float4 xa = ld4(xr + 0 * 256 + lo);
    float4 xb = ld4(xr + 1 * 256 + lo);
    float4 xc = ld4(xr + 2 * 256 + lo);
    float4 xd = ld4(xr + 3 * 256 + lo);

    // ---- cooperative staging of s2, u into LDS (hides under x latency) ----
#pragma unroll
    for (int k = 0; k < 2; ++k) {
        const int o = (k * 256 + tid) * 4;
        *reinterpret_cast<float4*>(&sS2[o]) = ld4(s2 + o);
        const float4 rv = ld4(g_rho + o);
        const float4 ev = ld4(eps + o);
        const float4 mv = ld4(g_mu + o);
        float4 u;
        float sp;
        sp  = fmaxf(rv.x, 0.0f) + __logf(1.0f + __expf(-fabsf(rv.x)));
        u.x = fmaf(sqrtf(sp), ev.x, mv.x) * (1.0f / 2048.0f);
        sp  = fmaxf(rv.y, 0.0f) + __logf(1.0f + __expf(-fabsf(rv.y)));
        u.y = fmaf(sqrtf(sp), ev.y, mv.y) * (1.0f / 2048.0f);
        sp  = fmaxf(rv.z, 0.0f) + __logf(1.0f + __expf(-fabsf(rv.z)));
        u.z = fmaf(sqrtf(sp), ev.z, mv.z) * (1.0f / 2048.0f);
        sp  = fmaxf(rv.w, 0.0f) + __logf(1.0f + __expf(-fabsf(rv.w)));
        u.w = fmaf(sqrtf(sp), ev.w, mv.w) * (1.0f / 2048.0f);
        *reinterpret_cast<float4*>(&sU[o]) = u;
    }
    __syncthreads();

    const float sg1 = (lane & 1) ? -1.0f : 1.0f;
    const float sg2 = (lane & 2) ? -1.0f : 1.0f;
    const float sg4 = (lane & 4) ? -1.0f : 1.0f;
    const float sg8 = (lane & 8) ? -1.0f : 1.0f;

    float v[32];

    // ---- batch 1 issued, then batch 0 consumed (frees its regs) ----
    float4 xe = ld4(xr + 4 * 256 + lo);
    float4 xf = ld4(xr + 5 * 256 + lo);
    float4 xg = ld4(xr + 6 * 256 + lo);
    float4 xh = ld4(xr + 7 * 256 + lo);

    {
        float4 sv;
        sv = ld4(&sS2[0 * 256 + lo]);
        v[ 0] = xa.x * sv.x; v[ 1] = xa.y * sv.y; v[ 2] = xa.z * sv.z; v[ 3] = xa.w * sv.w;
        sv = ld4(&sS2[1 * 256 + lo]);
        v[ 4] = xb.x * sv.x; v[ 5] = xb.y * sv.y; v[ 6] = xb.z * sv.z; v[ 7] = xb.w * sv.w;
        sv = ld4(&sS2[2 * 256 + lo]);
        v[ 8] = xc.x * sv.x; v[ 9] = xc.y * sv.y; v[10] = xc.z * sv.z; v[11] = xc.w * sv.w;
        sv = ld4(&sS2[3 * 256 + lo]);
        v[12] = xd.x * sv.x; v[13] = xd.y * sv.y; v[14] = xd.z * sv.z; v[15] = xd.w * sv.w;
        sv = ld4(&sS2[4 * 256 + lo]);
        v[16] = xe.x * sv.x; v[17] = xe.y * sv.y; v[18] = xe.z * sv.z; v[19] = xe.w * sv.w;
        sv = ld4(&sS2[5 * 256 + lo]);
        v[20] = xf.x * sv.x; v[21] = xf.y * sv.y; v[22] = xf.z * sv.z; v[23] = xf.w * sv.w;
        sv = ld4(&sS2[6 * 256 + lo]);
        v[24] = xg.x * sv.x; v[25] = xg.y * sv.y; v[26] = xg.z * sv.z; v[27] = xg.w * sv.w;
        sv = ld4(&sS2[7 * 256 + lo]);
        v[28] = xh.x * sv.x; v[29] = xh.y * sv.y; v[30] = xh.z * sv.z; v[31] = xh.w * sv.w;
    }

    fwht(v, sg1, sg2, sg4, sg8);

#pragma unroll
    for (int j = 0; j < 8; ++j) {
        const float4 uv = ld4(&sU[j * 256 + lo]);
        v[j * 4 + 0] *= uv.x;
        v[j * 4 + 1] *= uv.y;
        v[j * 4 + 2] *= uv.z;
        v[j * 4 + 3] *= uv.w;
    }

    fwht(v, sg1, sg2, sg4, sg8);

    // ---- epilogue: s1 from global (L1-hot), nontemporal store ----
    float* orow = out + row * WHVI_D;
#pragma unroll
    for (int j = 0; j < 8; ++j) {
        const float4 sv = ld4(s1 + j * 256 + lo);
        v4f ov;
        ov.x = v[j * 4 + 0] * sv.x;
        ov.y = v[j * 4 + 1] * sv.y;
        ov.z = v[j * 4 + 2] * sv.z;
        ov.w = v[j * 4 + 3] * sv.w;
        __builtin_nontemporal_store(ov, reinterpret_cast<v4f*>(orow + j * 256 + lo));
    }
}

extern "C" void kernel_launch(void* const* d_in, const int* in_sizes, int n_in,
                              void* d_out, int out_size, void* d_ws, size_t ws_size,
                              hipStream_t stream)
{
    const float* x     = (const float*)d_in[0];
    const float* s1    = (const float*)d_in[1];
    const float* s2    = (const float*)d_in[2];
    const float* g_mu  = (const float*)d_in[3];
    const float* g_rho = (const float*)d_in[4];
    const float* eps   = (const float*)d_in[5];
    // d_in[6] = H unused: fast Walsh-Hadamard transform instead.

    float* outp = (float*)d_out;
    const int rows = out_size / WHVI_D;              // 8192
    whvi_main_kernel<<<rows / 4, 256, 0, stream>>>(x, s1, s2, g_mu, g_rho, eps, outp);
}